// Round 9
// baseline (98.353 us; speedup 1.0000x reference)
//
#include <hip/hip_runtime.h>

#define HW   4096
#define Hh   64
#define Ww   64
#define NB   27
#define EPSBN 1e-5f

typedef _Float16 f16x8 __attribute__((ext_vector_type(8)));
typedef _Float16 f16x4 __attribute__((ext_vector_type(4)));
typedef _Float16 f16x2 __attribute__((ext_vector_type(2)));
typedef float    f32x4 __attribute__((ext_vector_type(4)));

// async global->LDS, 16B per lane; LDS dest = wave-uniform base + lane*16
__device__ __forceinline__ void gld_lds16(const void* g, void* l) {
    __builtin_amdgcn_global_load_lds(
        (const __attribute__((address_space(1))) unsigned int*)g,
        (__attribute__((address_space(3))) unsigned int*)l, 16, 0, 0);
}

// ---------------------------------------------------------------------------
// prep (merged): blocks [0,384): weights f32->f16; blocks [384,640): x
// (b,c,p) f32 -> xT (b,p,c) f16 via LDS transpose (pad-516 rows: write phase
// lane tx -> bank base tx%32 (2-way, free); read phase row-contiguous).
// Both sides fully coalesced in global memory.
// ---------------------------------------------------------------------------
__global__ __launch_bounds__(256)
void prep_kernel(const float* s0, const float* s1, const float* s2,
                 const float* s3, const float* s4, const float* s5,
                 _Float16* d0, _Float16* d1, _Float16* d2,
                 _Float16* d3, _Float16* d4, _Float16* d5,
                 const float* __restrict__ x, _Float16* __restrict__ xT)
{
    __shared__ _Float16 T[64][516];
    const int bid = blockIdx.x;
    const int tid = threadIdx.x;

    if (bid < 384) {                                 // ---- weight convert ----
        const int j  = bid >> 6;
        const int bx = bid & 63;
        const float* s = j==0?s0: j==1?s1: j==2?s2: j==3?s3: j==4?s4: s5;
        _Float16*  d = j==0?d0: j==1?d1: j==2?d2: j==3?d3: j==4?d4: d5;
        const int  n = (j==3 || j==4) ? 65536 : 131072;
        const int  i = (bx * 256 + tid) * 8;
        if (i < n) {
            f16x8 h;
            #pragma unroll
            for (int k = 0; k < 8; ++k) h[k] = (_Float16)s[i + k];
            *(f16x8*)(d + i) = h;
        }
        return;
    }
    // ---- x transpose+convert: 64 pixels x 512 channels per block ----
    const int t  = bid - 384;
    const int p0 = (t & 63) * 64;
    const int b  = t >> 6;
    const int tx = tid & 63;
    const int ty = tid >> 6;

    #pragma unroll 2
    for (int ch = 0; ch < 16; ++ch) {
        const int c0 = ch * 32 + ty * 8;
        const float* xp = x + ((size_t)b * 512 + c0) * HW + p0 + tx;
        f16x8 h;
        #pragma unroll
        for (int i = 0; i < 8; ++i) h[i] = (_Float16)xp[(size_t)i * HW];
        *(f16x8*)&T[tx][c0] = h;
    }
    __syncthreads();
    #pragma unroll 4
    for (int rr = 0; rr < 16; ++rr) {
        const int row = rr * 4 + ty;
        f16x8 h = *(const f16x8*)&T[row][tx * 8];
        *(f16x8*)(xT + ((size_t)b * HW + p0 + row) * 512 + tx * 8) = h;
    }
}

// ---------------------------------------------------------------------------
// 2-phase double-buffered MFMA GEMM: C[M,16384] = W[M,K] x inT[16384,K]^T.
// 128x128 tile, BK=64, 4 waves x (4x4 16x16x32 f16 frags).
// Per K-tile: issue global_load_lds for tile t+1 FIRST, then ds_read+MFMA
// tile t, then ONE __syncthreads() (its vmcnt(0)+lgkmcnt(0) drain covers the
// staged loads; load latency overlaps the 32 MFMAs). LDS XOR-swizzle via
// pre-swizzled global source + same XOR on ds_read (guide rule #21).
// mode: 0 = f16 out (p,c);  2 = f32 out (b,c,p)
// ---------------------------------------------------------------------------
struct GJob {
    const _Float16* in;   // (16384, K) f16
    const _Float16* w;    // (O, K) f16
    const float* b; const float* g; const float* be; const float* m; const float* v;
    _Float16* oh;
    float*    of;
};

__global__ __launch_bounds__(256)
void gemm128(GJob J0, GJob J1, GJob J2, int nmb0, int nmb01,
             int K, int JO, int mode)
{
    __shared__ _Float16 As[2][128 * 64];
    __shared__ _Float16 Bs[2][128 * 64];

    const int tid  = threadIdx.x;
    const int lane = tid & 63;
    const int w    = tid >> 6;
    const int lr   = lane & 15;
    const int lg   = lane >> 4;
    const int wm   = w & 1;
    const int wn   = w >> 1;

    const int bx = blockIdx.x;
    const int nb = (bx & 7) * 16 + (bx >> 3);   // XCD swizzle (128 % 8 == 0)
    const int mb = blockIdx.y;

    const bool i0 = mb < nmb0;
    const bool i1 = !i0 && mb < nmb01;
#define SELJ(f) (i0 ? J0.f : (i1 ? J1.f : J2.f))
    const _Float16* Jin = SELJ(in);
    const _Float16* Jw  = SELJ(w);
    const float* Jb  = SELJ(b);
    const float* Jg  = SELJ(g);
    const float* Jbe = SELJ(be);
    const float* Jm  = SELJ(m);
    const float* Jv  = SELJ(v);
    _Float16* Joh = SELJ(oh);
    float*    Jof = SELJ(of);
#undef SELJ
    const int obase = (mb - (i0 ? 0 : (i1 ? nmb0 : nmb01))) * 128;

    const int rowS = w * 32 + (lane >> 3);
    const int scol = (((lane & 7) ^ (lane >> 3)) << 3);
    const _Float16* aSrc = Jw  + (size_t)(obase + rowS) * K + scol;
    const _Float16* bSrc = Jin + (size_t)(nb * 128 + rowS) * K + scol;

    auto STAGE = [&](int buf, int rd) {
        const int kb = rd * 64;
        char* aD = (char*)&As[buf][0] + w * 4096;
        char* bD = (char*)&Bs[buf][0] + w * 4096;
        #pragma unroll
        for (int j = 0; j < 4; ++j)
            gld_lds16(aSrc + (size_t)j * 8 * K + kb, aD + j * 1024);
        #pragma unroll
        for (int j = 0; j < 4; ++j)
            gld_lds16(bSrc + (size_t)j * 8 * K + kb, bD + j * 1024);
    };

    f32x4 acc[4][4] = {};

    const int nr = K >> 6;
    STAGE(0, 0);
    __syncthreads();

    int cur = 0;
    for (int rd = 0; rd < nr; ++rd) {
        if (rd + 1 < nr) STAGE(cur ^ 1, rd + 1);    // prefetch next tile
        #pragma unroll
        for (int ks = 0; ks < 2; ++ks) {
            const int colx = (ks * 64 + lg * 16) ^ ((lr & 7) << 4);
            f16x8 afr[4], bfr[4];
            #pragma unroll
            for (int t = 0; t < 4; ++t) {
                afr[t] = *(const f16x8*)((const char*)&As[cur][0] + (wm * 64 + t * 16 + lr) * 128 + colx);
                bfr[t] = *(const f16x8*)((const char*)&Bs[cur][0] + (wn * 64 + t * 16 + lr) * 128 + colx);
            }
            #pragma unroll
            for (int ai = 0; ai < 4; ++ai)
                #pragma unroll
                for (int bj = 0; bj < 4; ++bj)
                    acc[ai][bj] = __builtin_amdgcn_mfma_f32_16x16x32_f16(
                        afr[ai], bfr[bj], acc[ai][bj], 0, 0, 0);
        }
        __syncthreads();                            // drains staged loads too
        cur ^= 1;
    }

    const int relu = (Jg != nullptr);
    #pragma unroll
    for (int ai = 0; ai < 4; ++ai) {
        const int o4 = obase + wm * 64 + ai * 16 + lg * 4;
        float sc[4], of_[4];
        #pragma unroll
        for (int r = 0; r < 4; ++r) {
            const int o = o4 + r;
            if (Jg) { float s = Jg[o] * rsqrtf(Jv[o] + EPSBN); sc[r] = s; of_[r] = fmaf(Jb[o] - Jm[o], s, Jbe[o]); }
            else    { sc[r] = 1.f; of_[r] = Jb[o]; }
        }
        #pragma unroll
        for (int bj = 0; bj < 4; ++bj) {
            const int pg = nb * 128 + wn * 64 + bj * 16 + lr;
            float vv[4];
            #pragma unroll
            for (int r = 0; r < 4; ++r) {
                float t = fmaf(acc[ai][bj][r], sc[r], of_[r]);
                vv[r] = relu ? fmaxf(t, 0.f) : t;
            }
            if (mode == 0) {
                f16x4 h;
                #pragma unroll
                for (int r = 0; r < 4; ++r) h[r] = (_Float16)vv[r];
                *(f16x4*)(Joh + (size_t)pg * JO + o4) = h;
            } else {
                #pragma unroll
                for (int r = 0; r < 4; ++r)
                    Jof[((size_t)(pg >> 12) * JO + o4 + r) * HW + (pg & 4095)] = vv[r];
            }
        }
    }
}

// ---------------------------------------------------------------------------
// Fused attention: sim + softmax + PV, all buffers (b,p,256) f16.
// Thread = (pixel, 8-ch slot); 32 consecutive lanes read one 512B neighbor
// row coalesced. fdot2 sim partials; shfl_xor reduce over 32 slot-lanes;
// in-register softmax; OOB zeroed via valf (matches zero-padded unfold).
// ---------------------------------------------------------------------------
__global__ __launch_bounds__(256)
void attn_fused(const _Float16* __restrict__ keyT, const _Float16* __restrict__ qryT,
                const _Float16* __restrict__ valT, _Float16* __restrict__ ctxT)
{
    const int tid  = threadIdx.x;
    const int slot = tid & 31;
    const int b    = blockIdx.y;
    const int p    = blockIdx.x * 8 + (tid >> 5);
    const int y    = p >> 6;
    const int xc   = p & 63;

    int   idx[NB];
    float valf[NB];
    #pragma unroll
    for (int n = 0; n < NB; ++n) {
        const int d  = (n < 9) ? 1 : (n < 18 ? 2 : 4);
        const int i  = (n / 3) % 3 - 1;
        const int j  = n % 3 - 1;
        const int yy = y + i * d, xx = xc + j * d;
        const bool ok = ((unsigned)yy < (unsigned)Hh) && ((unsigned)xx < (unsigned)Ww);
        idx[n]  = min(max(yy, 0), Hh - 1) * Ww + min(max(xx, 0), Ww - 1);
        valf[n] = ok ? 1.f : 0.f;
    }

    const size_t base = (size_t)b * HW * 256 + slot * 8;
    const f16x8 q8 = *(const f16x8*)(qryT + base + (size_t)p * 256);

    f16x2 qp[4];
    qp[0] = __builtin_shufflevector(q8, q8, 0, 1);
    qp[1] = __builtin_shufflevector(q8, q8, 2, 3);
    qp[2] = __builtin_shufflevector(q8, q8, 4, 5);
    qp[3] = __builtin_shufflevector(q8, q8, 6, 7);

    float sim[NB];
    #pragma unroll
    for (int n = 0; n < NB; ++n) {
        const f16x8 k8 = *(const f16x8*)(keyT + base + (size_t)idx[n] * 256);
        float s = 0.f;
        s = __builtin_amdgcn_fdot2(__builtin_shufflevector(k8, k8, 0, 1), qp[0], s, false);
        s = __builtin_amdgcn_fdot2(__builtin_shufflevector(k8, k8, 2, 3), qp[1], s, false);
        s = __builtin_amdgcn_fdot2(__builtin_shufflevector(k8, k8, 4, 5), qp[2], s, false);
        s = __builtin_amdgcn_fdot2(__builtin_shufflevector(k8, k8, 6, 7), qp[3], s, false);
        sim[n] = s;
    }

    #pragma unroll
    for (int n = 0; n < NB; ++n) {
        float s = sim[n];
        s += __shfl_xor(s, 1);
        s += __shfl_xor(s, 2);
        s += __shfl_xor(s, 4);
        s += __shfl_xor(s, 8);
        s += __shfl_xor(s, 16);
        sim[n] = s * valf[n];
    }

    float mx = sim[0];
    #pragma unroll
    for (int n = 1; n < NB; ++n) mx = fmaxf(mx, sim[n]);
    float sum = 0.f;
    #pragma unroll
    for (int n = 0; n < NB; ++n) { sim[n] = __expf(sim[n] - mx); sum += sim[n]; }
    const float inv = 1.f / sum;
    #pragma unroll
    for (int n = 0; n < NB; ++n) sim[n] = sim[n] * inv * valf[n];

    float acc[8];
    #pragma unroll
    for (int i = 0; i < 8; ++i) acc[i] = 0.f;
    #pragma unroll
    for (int n = 0; n < NB; ++n) {
        const f16x8 v8 = *(const f16x8*)(valT + base + (size_t)idx[n] * 256);
        const float w = sim[n];
        #pragma unroll
        for (int i = 0; i < 8; ++i) acc[i] = fmaf(w, (float)v8[i], acc[i]);
    }

    f16x8 h;
    #pragma unroll
    for (int i = 0; i < 8; ++i) h[i] = (_Float16)acc[i];
    *(f16x8*)(ctxT + base + (size_t)p * 256) = h;
}

extern "C" void kernel_launch(void* const* d_in, const int* in_sizes, int n_in,
                              void* d_out, int out_size, void* d_ws, size_t ws_size,
                              hipStream_t stream)
{
    (void)in_sizes; (void)n_in; (void)out_size; (void)ws_size;
    const float* x     = (const float*)d_in[0];
    const float* k1_w  = (const float*)d_in[1];
    const float* k1_b  = (const float*)d_in[2];
    const float* k1_g  = (const float*)d_in[3];
    const float* k1_be = (const float*)d_in[4];
    const float* k1_m  = (const float*)d_in[5];
    const float* k1_v  = (const float*)d_in[6];
    const float* k2_w  = (const float*)d_in[7];
    const float* k2_b  = (const float*)d_in[8];
    const float* k2_g  = (const float*)d_in[9];
    const float* k2_be = (const float*)d_in[10];
    const float* k2_m  = (const float*)d_in[11];
    const float* k2_v  = (const float*)d_in[12];
    const float* q1_w  = (const float*)d_in[13];
    const float* q1_b  = (const float*)d_in[14];
    const float* q1_g  = (const float*)d_in[15];
    const float* q1_be = (const float*)d_in[16];
    const float* q1_m  = (const float*)d_in[17];
    const float* q1_v  = (const float*)d_in[18];
    const float* q2_w  = (const float*)d_in[19];
    const float* q2_b  = (const float*)d_in[20];
    const float* q2_g  = (const float*)d_in[21];
    const float* q2_be = (const float*)d_in[22];
    const float* q2_m  = (const float*)d_in[23];
    const float* q2_v  = (const float*)d_in[24];
    const float* v_w   = (const float*)d_in[25];
    const float* v_b   = (const float*)d_in[26];
    const float* w_w   = (const float*)d_in[27];
    const float* w_b   = (const float*)d_in[28];

    _Float16* hw = (_Float16*)d_ws;
    const size_t SX = (size_t)4 * HW * 512;
    const size_t SH = (size_t)4 * HW * 256;
    _Float16* xT    = hw;
    _Float16* wv_h  = xT + SX;
    _Float16* wk1_h = wv_h  + 131072;
    _Float16* wq1_h = wk1_h + 131072;
    _Float16* wk2_h = wq1_h + 131072;
    _Float16* wq2_h = wk2_h + 65536;
    _Float16* ww_h  = wq2_h + 65536;
    _Float16* k1T   = ww_h  + 131072;
    _Float16* q1T   = k1T + SH;
    _Float16* valT  = q1T + SH;
    _Float16* ctxT  = valT + SH;
    _Float16* keyPC = ctxT + SH;
    _Float16* qryPC = keyPC + SH;

    // prep: 384 weight blocks + 256 x-transpose blocks in one launch
    prep_kernel<<<640, 256, 0, stream>>>(v_w, k1_w, q1_w, k2_w, q2_w, w_w,
                                         wv_h, wk1_h, wq1_h, wk2_h, wq2_h, ww_h,
                                         x, xT);

    GJob jv  = { xT,  wv_h,  v_b,  nullptr, nullptr, nullptr, nullptr, valT,  nullptr };
    GJob jk1 = { xT,  wk1_h, k1_b, k1_g, k1_be, k1_m, k1_v,            k1T,   nullptr };
    GJob jq1 = { xT,  wq1_h, q1_b, q1_g, q1_be, q1_m, q1_v,            q1T,   nullptr };
    GJob jk2 = { k1T, wk2_h, k2_b, k2_g, k2_be, k2_m, k2_v,            keyPC, nullptr };
    GJob jq2 = { q1T, wq2_h, q2_b, q2_g, q2_be, q2_m, q2_v,            qryPC, nullptr };
    GJob jw  = { ctxT, ww_h, w_b,  nullptr, nullptr, nullptr, nullptr, nullptr, (float*)d_out };

    // stage 1: v | k1 | q1  (2 m-blocks each), K=512, out f16 (p,c)
    gemm128<<<dim3(128, 6), 256, 0, stream>>>(jv, jk1, jq1, 2, 4, 512, 256, 0);
    // stage 2: k2 | q2, K=256, out f16 (p,c)
    gemm128<<<dim3(128, 4), 256, 0, stream>>>(jk2, jq2, jq2, 2, 4, 256, 256, 0);
    // stage 3: fused sim+softmax+PV -> ctxT (p,c) f16
    attn_fused<<<dim3(512, 4), 256, 0, stream>>>(keyPC, qryPC, valT, ctxT);
    // stage 4: final conv, K=256, out f32 (b,c,p) -> d_out
    gemm128<<<dim3(128, 4), 256, 0, stream>>>(jw, jw, jw, 4, 4, 256, 512, 2);
}

// Round 10
// 96.127 us; speedup vs baseline: 1.0232x; 1.0232x over previous
//
#include <hip/hip_runtime.h>

#define HW   4096
#define Hh   64
#define Ww   64
#define NB   27
#define EPSBN 1e-5f

typedef _Float16 f16x8 __attribute__((ext_vector_type(8)));
typedef _Float16 f16x4 __attribute__((ext_vector_type(4)));
typedef _Float16 f16x2 __attribute__((ext_vector_type(2)));
typedef float    f32x4 __attribute__((ext_vector_type(4)));

// async global->LDS, 16B per lane; LDS dest = wave-uniform base + lane*16
__device__ __forceinline__ void gld_lds16(const void* g, void* l) {
    __builtin_amdgcn_global_load_lds(
        (const __attribute__((address_space(1))) unsigned int*)g,
        (__attribute__((address_space(3))) unsigned int*)l, 16, 0, 0);
}

// ---------------------------------------------------------------------------
// prep: weights f32 -> f16 only (x-transpose eliminated: stage-1 GEMM now
// reg-stages f32 x directly into LDS with in-register convert).
// ---------------------------------------------------------------------------
__global__ __launch_bounds__(256)
void prep_kernel(const float* s0, const float* s1, const float* s2,
                 const float* s3, const float* s4, const float* s5,
                 _Float16* d0, _Float16* d1, _Float16* d2,
                 _Float16* d3, _Float16* d4, _Float16* d5)
{
    const int bid = blockIdx.x;
    const int j  = bid >> 6;
    const int bx = bid & 63;
    const float* s = j==0?s0: j==1?s1: j==2?s2: j==3?s3: j==4?s4: s5;
    _Float16*  d = j==0?d0: j==1?d1: j==2?d2: j==3?d3: j==4?d4: d5;
    const int  n = (j==3 || j==4) ? 65536 : 131072;
    const int  i = (bx * 256 + threadIdx.x) * 8;
    if (i < n) {
        f16x8 h;
        #pragma unroll
        for (int k = 0; k < 8; ++k) h[k] = (_Float16)s[i + k];
        *(f16x8*)(d + i) = h;
    }
}

// ---------------------------------------------------------------------------
// 2-phase double-buffered MFMA GEMM: C[M,16384] = W[M,K] x B[16384,K]^T.
// 128x128 tile, BK=64, 4 waves x (4x4 16x16x32 f16 frags).
// B operand source (block-uniform per dispatch):
//   Jin  != null: f16 (p,c) rows, staged via global_load_lds (pre-swizzled src)
//   Jxf  != null: f32 x in (b,c,p) -- reg-staged: coalesced 256B channel-row
//                 loads (lane=pixel), f32->f16 convert, swizzled ds_write_b128.
//                 T14 split: loads issued BEFORE the MFMA cluster, convert+
//                 ds_write AFTER (vmcnt hides under 64 MFMAs).
// LDS XOR-swizzle (byte col ^= (row&7)<<4) on both write and read sides.
// 1-D locality grid: bid=j*8+i -> XCD i owns nb=i*16+j/nmb, mb=j%nmb, so
// mb-blocks sharing a B-chunk run back-to-back on one XCD (L2 reuse).
// mode: 0 = f16 out (p,c);  2 = f32 out (b,c,p)
// ---------------------------------------------------------------------------
struct GJob {
    const _Float16* in;   // (16384, K) f16, or null
    const float*    xf;   // (b,c,p) f32, or null
    const _Float16* w;    // (O, K) f16
    const float* b; const float* g; const float* be; const float* m; const float* v;
    _Float16* oh;
    float*    of;
};

__global__ __launch_bounds__(256)
void gemm128(GJob J0, GJob J1, GJob J2, int nmb0, int nmb01, int nmbTot,
             int K, int JO, int mode)
{
    __shared__ _Float16 As[2][128 * 64];
    __shared__ _Float16 Bs[2][128 * 64];

    const int tid  = threadIdx.x;
    const int lane = tid & 63;
    const int w    = tid >> 6;
    const int lr   = lane & 15;
    const int lg   = lane >> 4;
    const int wm   = w & 1;
    const int wn   = w >> 1;

    // locality-ordered decode
    const int bid = blockIdx.x;
    const int xcd = bid & 7;
    const int jj  = bid >> 3;                   // 0 .. 16*nmbTot-1
    const int nb  = xcd * 16 + jj / nmbTot;
    const int mb  = jj % nmbTot;

    const bool i0 = mb < nmb0;
    const bool i1 = !i0 && mb < nmb01;
#define SELJ(f) (i0 ? J0.f : (i1 ? J1.f : J2.f))
    const _Float16* Jin = SELJ(in);
    const float*    Jxf = SELJ(xf);
    const _Float16* Jw  = SELJ(w);
    const float* Jb  = SELJ(b);
    const float* Jg  = SELJ(g);
    const float* Jbe = SELJ(be);
    const float* Jm  = SELJ(m);
    const float* Jv  = SELJ(v);
    _Float16* Joh = SELJ(oh);
    float*    Jof = SELJ(of);
#undef SELJ
    const int obase = (mb - (i0 ? 0 : (i1 ? nmb0 : nmb01))) * 128;

    const int rowS = w * 32 + (lane >> 3);
    const int scol = (((lane & 7) ^ (lane >> 3)) << 3);
    const _Float16* aSrc = Jw + (size_t)(obase + rowS) * K + scol;
    const _Float16* bSrc = Jin ? (Jin + (size_t)(nb * 128 + rowS) * K + scol) : nullptr;

    // f32 direct-B staging params
    const int h    = w & 1;                     // pixel half (64 px)
    const int q    = w >> 1;                    // channel half (32 ch)
    const int brow = h * 64 + lane;             // LDS row this lane writes
    const int bxor = (brow & 7) << 4;
    const float* xbase = nullptr;
    if (Jxf) {
        const int bb = nb >> 5;
        const int pp = (nb & 31) * 128 + h * 64 + lane;
        xbase = Jxf + (size_t)bb * 512 * HW + pp;     // + c*HW per channel
    }

    float fr[4][8];                             // staged f32 (static-indexed)

    auto STAGE_A = [&](int buf, int rd) {
        const int kb = rd * 64;
        char* aD = (char*)&As[buf][0] + w * 4096;
        #pragma unroll
        for (int j2 = 0; j2 < 4; ++j2)
            gld_lds16(aSrc + (size_t)j2 * 8 * K + kb, aD + j2 * 1024);
    };
    auto STAGE_B_LDS = [&](int buf, int rd) {
        const int kb = rd * 64;
        char* bD = (char*)&Bs[buf][0] + w * 4096;
        #pragma unroll
        for (int j2 = 0; j2 < 4; ++j2)
            gld_lds16(bSrc + (size_t)j2 * 8 * K + kb, bD + j2 * 1024);
    };
    auto ISSUE_BX = [&](int rd) {               // coalesced f32 loads -> regs
        const int kb = rd * 64 + q * 32;
        #pragma unroll
        for (int g2 = 0; g2 < 4; ++g2)
            #pragma unroll
            for (int i2 = 0; i2 < 8; ++i2)
                fr[g2][i2] = xbase[(size_t)(kb + g2 * 8 + i2) * HW];
    };
    auto WRITE_BX = [&](int buf) {              // convert + swizzled ds_write
        #pragma unroll
        for (int g2 = 0; g2 < 4; ++g2) {
            f16x8 hv;
            #pragma unroll
            for (int i2 = 0; i2 < 8; ++i2) hv[i2] = (_Float16)fr[g2][i2];
            *(f16x8*)((char*)&Bs[buf][0] + brow * 128 + ((q * 64 + g2 * 16) ^ bxor)) = hv;
        }
    };

    f32x4 acc[4][4] = {};
    const int nr = K >> 6;

    // prologue: stage tile 0
    if (Jxf) { ISSUE_BX(0); WRITE_BX(0); }
    else     { STAGE_B_LDS(0, 0); }
    STAGE_A(0, 0);
    __syncthreads();

    int cur = 0;
    for (int rd = 0; rd < nr; ++rd) {
        const bool more = (rd + 1 < nr);
        if (more) {
            STAGE_A(cur ^ 1, rd + 1);
            if (Jxf) ISSUE_BX(rd + 1);
            else     STAGE_B_LDS(cur ^ 1, rd + 1);
        }
        #pragma unroll
        for (int ks = 0; ks < 2; ++ks) {
            const int colx = (ks * 64 + lg * 16) ^ ((lr & 7) << 4);
            f16x8 afr[4], bfr[4];
            #pragma unroll
            for (int t = 0; t < 4; ++t) {
                afr[t] = *(const f16x8*)((const char*)&As[cur][0] + (wm * 64 + t * 16 + lr) * 128 + colx);
                bfr[t] = *(const f16x8*)((const char*)&Bs[cur][0] + (wn * 64 + t * 16 + lr) * 128 + colx);
            }
            #pragma unroll
            for (int ai = 0; ai < 4; ++ai)
                #pragma unroll
                for (int bj = 0; bj < 4; ++bj)
                    acc[ai][bj] = __builtin_amdgcn_mfma_f32_16x16x32_f16(
                        afr[ai], bfr[bj], acc[ai][bj], 0, 0, 0);
        }
        if (Jxf && more) WRITE_BX(cur ^ 1);     // vmcnt wait lands here, after MFMAs
        __syncthreads();                        // drains gld_lds + ds_writes
        cur ^= 1;
    }

    const int relu = (Jg != nullptr);
    #pragma unroll
    for (int ai = 0; ai < 4; ++ai) {
        const int o4 = obase + wm * 64 + ai * 16 + lg * 4;
        float sc[4], of_[4];
        #pragma unroll
        for (int r = 0; r < 4; ++r) {
            const int o = o4 + r;
            if (Jg) { float s = Jg[o] * rsqrtf(Jv[o] + EPSBN); sc[r] = s; of_[r] = fmaf(Jb[o] - Jm[o], s, Jbe[o]); }
            else    { sc[r] = 1.f; of_[r] = Jb[o]; }
        }
        #pragma unroll
        for (int bj = 0; bj < 4; ++bj) {
            const int pg = nb * 128 + wn * 64 + bj * 16 + lr;
            float vv[4];
            #pragma unroll
            for (int r = 0; r < 4; ++r) {
                float t = fmaf(acc[ai][bj][r], sc[r], of_[r]);
                vv[r] = relu ? fmaxf(t, 0.f) : t;
            }
            if (mode == 0) {
                f16x4 hh;
                #pragma unroll
                for (int r = 0; r < 4; ++r) hh[r] = (_Float16)vv[r];
                *(f16x4*)(Joh + (size_t)pg * JO + o4) = hh;
            } else {
                #pragma unroll
                for (int r = 0; r < 4; ++r)
                    Jof[((size_t)(pg >> 12) * JO + o4 + r) * HW + (pg & 4095)] = vv[r];
            }
        }
    }
}

// ---------------------------------------------------------------------------
// Fused attention: sim + softmax + PV, all buffers (b,p,256) f16.
// Thread = (pixel, 8-ch slot); 32 consecutive lanes read one 512B neighbor
// row coalesced. fdot2 sim partials; shfl_xor reduce over 32 slot-lanes;
// in-register softmax; OOB zeroed via valf (matches zero-padded unfold).
// ---------------------------------------------------------------------------
__global__ __launch_bounds__(256)
void attn_fused(const _Float16* __restrict__ keyT, const _Float16* __restrict__ qryT,
                const _Float16* __restrict__ valT, _Float16* __restrict__ ctxT)
{
    const int tid  = threadIdx.x;
    const int slot = tid & 31;
    const int b    = blockIdx.y;
    const int p    = blockIdx.x * 8 + (tid >> 5);
    const int y    = p >> 6;
    const int xc   = p & 63;

    int   idx[NB];
    float valf[NB];
    #pragma unroll
    for (int n = 0; n < NB; ++n) {
        const int d  = (n < 9) ? 1 : (n < 18 ? 2 : 4);
        const int i  = (n / 3) % 3 - 1;
        const int j  = n % 3 - 1;
        const int yy = y + i * d, xx = xc + j * d;
        const bool ok = ((unsigned)yy < (unsigned)Hh) && ((unsigned)xx < (unsigned)Ww);
        idx[n]  = min(max(yy, 0), Hh - 1) * Ww + min(max(xx, 0), Ww - 1);
        valf[n] = ok ? 1.f : 0.f;
    }

    const size_t base = (size_t)b * HW * 256 + slot * 8;
    const f16x8 q8 = *(const f16x8*)(qryT + base + (size_t)p * 256);

    f16x2 qp[4];
    qp[0] = __builtin_shufflevector(q8, q8, 0, 1);
    qp[1] = __builtin_shufflevector(q8, q8, 2, 3);
    qp[2] = __builtin_shufflevector(q8, q8, 4, 5);
    qp[3] = __builtin_shufflevector(q8, q8, 6, 7);

    float sim[NB];
    #pragma unroll
    for (int n = 0; n < NB; ++n) {
        const f16x8 k8 = *(const f16x8*)(keyT + base + (size_t)idx[n] * 256);
        float s = 0.f;
        s = __builtin_amdgcn_fdot2(__builtin_shufflevector(k8, k8, 0, 1), qp[0], s, false);
        s = __builtin_amdgcn_fdot2(__builtin_shufflevector(k8, k8, 2, 3), qp[1], s, false);
        s = __builtin_amdgcn_fdot2(__builtin_shufflevector(k8, k8, 4, 5), qp[2], s, false);
        s = __builtin_amdgcn_fdot2(__builtin_shufflevector(k8, k8, 6, 7), qp[3], s, false);
        sim[n] = s;
    }

    #pragma unroll
    for (int n = 0; n < NB; ++n) {
        float s = sim[n];
        s += __shfl_xor(s, 1);
        s += __shfl_xor(s, 2);
        s += __shfl_xor(s, 4);
        s += __shfl_xor(s, 8);
        s += __shfl_xor(s, 16);
        sim[n] = s * valf[n];
    }

    float mx = sim[0];
    #pragma unroll
    for (int n = 1; n < NB; ++n) mx = fmaxf(mx, sim[n]);
    float sum = 0.f;
    #pragma unroll
    for (int n = 0; n < NB; ++n) { sim[n] = __expf(sim[n] - mx); sum += sim[n]; }
    const float inv = 1.f / sum;
    #pragma unroll
    for (int n = 0; n < NB; ++n) sim[n] = sim[n] * inv * valf[n];

    float acc[8];
    #pragma unroll
    for (int i = 0; i < 8; ++i) acc[i] = 0.f;
    #pragma unroll
    for (int n = 0; n < NB; ++n) {
        const f16x8 v8 = *(const f16x8*)(valT + base + (size_t)idx[n] * 256);
        const float w = sim[n];
        #pragma unroll
        for (int i = 0; i < 8; ++i) acc[i] = fmaf(w, (float)v8[i], acc[i]);
    }

    f16x8 h;
    #pragma unroll
    for (int i = 0; i < 8; ++i) h[i] = (_Float16)acc[i];
    *(f16x8*)(ctxT + base + (size_t)p * 256) = h;
}

extern "C" void kernel_launch(void* const* d_in, const int* in_sizes, int n_in,
                              void* d_out, int out_size, void* d_ws, size_t ws_size,
                              hipStream_t stream)
{
    (void)in_sizes; (void)n_in; (void)out_size; (void)ws_size;
    const float* x     = (const float*)d_in[0];
    const float* k1_w  = (const float*)d_in[1];
    const float* k1_b  = (const float*)d_in[2];
    const float* k1_g  = (const float*)d_in[3];
    const float* k1_be = (const float*)d_in[4];
    const float* k1_m  = (const float*)d_in[5];
    const float* k1_v  = (const float*)d_in[6];
    const float* k2_w  = (const float*)d_in[7];
    const float* k2_b  = (const float*)d_in[8];
    const float* k2_g  = (const float*)d_in[9];
    const float* k2_be = (const float*)d_in[10];
    const float* k2_m  = (const float*)d_in[11];
    const float* k2_v  = (const float*)d_in[12];
    const float* q1_w  = (const float*)d_in[13];
    const float* q1_b  = (const float*)d_in[14];
    const float* q1_g  = (const float*)d_in[15];
    const float* q1_be = (const float*)d_in[16];
    const float* q1_m  = (const float*)d_in[17];
    const float* q1_v  = (const float*)d_in[18];
    const float* q2_w  = (const float*)d_in[19];
    const float* q2_b  = (const float*)d_in[20];
    const float* q2_g  = (const float*)d_in[21];
    const float* q2_be = (const float*)d_in[22];
    const float* q2_m  = (const float*)d_in[23];
    const float* q2_v  = (const float*)d_in[24];
    const float* v_w   = (const float*)d_in[25];
    const float* v_b   = (const float*)d_in[26];
    const float* w_w   = (const float*)d_in[27];
    const float* w_b   = (const float*)d_in[28];

    _Float16* hw = (_Float16*)d_ws;
    const size_t SH = (size_t)4 * HW * 256;
    _Float16* wv_h  = hw;
    _Float16* wk1_h = wv_h  + 131072;
    _Float16* wq1_h = wk1_h + 131072;
    _Float16* wk2_h = wq1_h + 131072;
    _Float16* wq2_h = wk2_h + 65536;
    _Float16* ww_h  = wq2_h + 65536;
    _Float16* k1T   = ww_h  + 131072;
    _Float16* q1T   = k1T + SH;
    _Float16* valT  = q1T + SH;
    _Float16* ctxT  = valT + SH;
    _Float16* keyPC = ctxT + SH;
    _Float16* qryPC = keyPC + SH;

    prep_kernel<<<384, 256, 0, stream>>>(v_w, k1_w, q1_w, k2_w, q2_w, w_w,
                                         wv_h, wk1_h, wq1_h, wk2_h, wq2_h, ww_h);

    GJob jv  = { nullptr, x, wv_h,  v_b,  nullptr, nullptr, nullptr, nullptr, valT,  nullptr };
    GJob jk1 = { nullptr, x, wk1_h, k1_b, k1_g, k1_be, k1_m, k1_v,            k1T,   nullptr };
    GJob jq1 = { nullptr, x, wq1_h, q1_b, q1_g, q1_be, q1_m, q1_v,            q1T,   nullptr };
    GJob jk2 = { k1T, nullptr, wk2_h, k2_b, k2_g, k2_be, k2_m, k2_v,          keyPC, nullptr };
    GJob jq2 = { q1T, nullptr, wq2_h, q2_b, q2_g, q2_be, q2_m, q2_v,          qryPC, nullptr };
    GJob jw  = { ctxT, nullptr, ww_h, w_b,  nullptr, nullptr, nullptr, nullptr, nullptr, (float*)d_out };

    // stage 1: v | k1 | q1  (2 m-blocks each), K=512, B = f32 x direct
    gemm128<<<768, 256, 0, stream>>>(jv, jk1, jq1, 2, 4, 6, 512, 256, 0);
    // stage 2: k2 | q2, K=256, out f16 (p,c)
    gemm128<<<512, 256, 0, stream>>>(jk2, jq2, jq2, 2, 4, 4, 256, 256, 0);
    // stage 3: fused sim+softmax+PV -> ctxT (p,c) f16
    attn_fused<<<dim3(512, 4), 256, 0, stream>>>(keyPC, qryPC, valT, ctxT);
    // stage 4: final conv, K=256, out f32 (b,c,p) -> d_out
    gemm128<<<512, 256, 0, stream>>>(jw, jw, jw, 4, 4, 4, 256, 512, 2);
}